// Round 7
// baseline (140.193 us; speedup 1.0000x reference)
//
#include <hip/hip_runtime.h>
#include <hip/hip_bf16.h>
#include <math.h>

#define B 4
#define T 128
#define C 512
#define NH 8
#define HS 64
#define BH (B*NH)   // 32

typedef __attribute__((ext_vector_type(8))) short bf16x8;
typedef __attribute__((ext_vector_type(4))) float f32x4;

__device__ __forceinline__ unsigned short bfc(float x) {
    return __builtin_bit_cast(unsigned short, __float2bfloat16(x));
}
__device__ __forceinline__ float b2f(unsigned short u) {
    unsigned int x = ((unsigned int)u) << 16;
    return __builtin_bit_cast(float, x);
}
__device__ __forceinline__ unsigned int pk_bf16(float a, float b) {
    return (unsigned int)bfc(a) | ((unsigned int)bfc(b) << 16);
}

// ---------------- prep: cvt X + transpose-cvt 4 weights + wcomb (2 slices) ----------------
__global__ __launch_bounds__(256) void prep_kernel(
    const float* __restrict__ X, const float* __restrict__ Wp0, const float* __restrict__ Wp1,
    const float* __restrict__ Wp2, const float* __restrict__ Wc,
    const float* __restrict__ Wv0, const float* __restrict__ Wv1,
    unsigned short* __restrict__ Xb, unsigned short* __restrict__ W0T, unsigned short* __restrict__ W1T,
    unsigned short* __restrict__ W2T, unsigned short* __restrict__ WcT,
    unsigned short* __restrict__ We0T, unsigned short* __restrict__ We1T)
{
    __shared__ float Ls[64][69];
    __shared__ float As[16][68];
    __shared__ float Bs[16][68];
    const int z = blockIdx.z;
    const int tid = threadIdx.x;
    if (z == 0) {
        const int r0 = blockIdx.y * 64, c0 = blockIdx.x * 64;
        #pragma unroll
        for (int it = 0; it < 2; ++it) {
            const int q = tid + it * 256;
            const int row = q >> 3, c8 = (q & 7) * 8;
            const float4 a = *(const float4*)&X[(size_t)(r0 + row) * 512 + c0 + c8];
            const float4 b = *(const float4*)&X[(size_t)(r0 + row) * 512 + c0 + c8 + 4];
            uint4 o;
            o.x = pk_bf16(a.x, a.y);
            o.y = pk_bf16(a.z, a.w);
            o.z = pk_bf16(b.x, b.y);
            o.w = pk_bf16(b.z, b.w);
            *(uint4*)&Xb[(size_t)(r0 + row) * 512 + c0 + c8] = o;
        }
        return;
    }
    if (z <= 4) {
        const int r0 = blockIdx.y * 64, c0 = blockIdx.x * 64;
        const float* W = (z == 1) ? Wp0 : (z == 2) ? Wp1 : (z == 3) ? Wp2 : Wc;
        unsigned short* WT = (z == 1) ? W0T : (z == 2) ? W1T : (z == 3) ? W2T : WcT;
        #pragma unroll
        for (int it = 0; it < 4; ++it) {
            const int q = tid + it * 256;
            const int row = q >> 4, c4 = (q & 15) * 4;
            const float4 v = *(const float4*)&W[(size_t)(r0 + row) * 512 + c0 + c4];
            Ls[row][c4 + 0] = v.x; Ls[row][c4 + 1] = v.y; Ls[row][c4 + 2] = v.z; Ls[row][c4 + 3] = v.w;
        }
        __syncthreads();
        #pragma unroll
        for (int it = 0; it < 2; ++it) {
            const int q = tid + it * 256;
            const int nrow = q >> 3, k8 = (q & 7) * 8;
            uint4 o;
            o.x = pk_bf16(Ls[k8 + 0][nrow], Ls[k8 + 1][nrow]);
            o.y = pk_bf16(Ls[k8 + 2][nrow], Ls[k8 + 3][nrow]);
            o.z = pk_bf16(Ls[k8 + 4][nrow], Ls[k8 + 5][nrow]);
            o.w = pk_bf16(Ls[k8 + 6][nrow], Ls[k8 + 7][nrow]);
            *(uint4*)&WT[(size_t)(c0 + nrow) * 512 + r0 + k8] = o;
        }
        return;
    }
    // z==5/6: We = Wp @ blockdiag(Wv), transposed bf16 out
    const float* A  = (z == 5) ? Wp1 : Wp2;
    const float* Wv = (z == 5) ? Wv0 : Wv1;
    unsigned short* O = (z == 5) ? We0T : We1T;
    const int h = blockIdx.x;
    const int m0 = blockIdx.y * 64;
    const int tx = tid & 15, ty = tid >> 4;
    const int arow = tid >> 2, acol = (tid & 3) * 4;
    const int brow = tid >> 4, bcol = (tid & 15) * 4;
    float acc[4][4] = {};
    for (int k0 = 0; k0 < 64; k0 += 16) {
        const float4 av = *(const float4*)&A[(size_t)(m0 + arow) * 512 + h * 64 + k0 + acol];
        const float4 bv = *(const float4*)&Wv[(size_t)(k0 + brow) * 64 + bcol];
        __syncthreads();
        As[acol + 0][arow] = av.x; As[acol + 1][arow] = av.y;
        As[acol + 2][arow] = av.z; As[acol + 3][arow] = av.w;
        *(float4*)&Bs[brow][bcol] = bv;
        __syncthreads();
        #pragma unroll
        for (int kk = 0; kk < 16; ++kk) {
            const float4 a4 = *(const float4*)&As[kk][ty * 4];
            const float4 b4 = *(const float4*)&Bs[kk][tx * 4];
            const float ar[4] = {a4.x, a4.y, a4.z, a4.w};
            const float br[4] = {b4.x, b4.y, b4.z, b4.w};
            #pragma unroll
            for (int r = 0; r < 4; ++r)
                #pragma unroll
                for (int c = 0; c < 4; ++c)
                    acc[r][c] = fmaf(ar[r], br[c], acc[r][c]);
        }
    }
    #pragma unroll
    for (int r = 0; r < 4; ++r)
        #pragma unroll
        for (int c = 0; c < 4; ++c)
            O[(size_t)(h * 64 + tx * 4 + c) * 512 + (m0 + ty * 4 + r)] = bfc(acc[r][c]);
}

// ---------------- bf16 MFMA projection GEMM; z==2 emits rowsums rr, never stores p2 ----------------
__global__ __launch_bounds__(256) void projmm_kernel(
    const unsigned short* __restrict__ Xb,
    const unsigned short* __restrict__ W0T, const unsigned short* __restrict__ W1T,
    const unsigned short* __restrict__ W2T,
    const unsigned short* __restrict__ We0T, const unsigned short* __restrict__ We1T,
    unsigned short* __restrict__ p0b, unsigned short* __restrict__ p1b,
    float* __restrict__ V0, unsigned short* __restrict__ V1T, float* __restrict__ rr)
{
    __shared__ __align__(16) unsigned short As[64][72];
    __shared__ __align__(16) unsigned short Bs[64][72];
    __shared__ float sRS[4][64];
    const int z = blockIdx.z;
    const unsigned short* WT = (z == 0) ? W0T : (z == 1) ? W1T : (z == 2) ? W2T : (z == 3) ? We0T : We1T;
    const int m0 = blockIdx.y * 64, n0 = blockIdx.x * 64;
    const int tid = threadIdx.x;
    const int w = tid >> 6, lane = tid & 63, quad = lane >> 4, l16 = lane & 15;
    f32x4 acc[4];
    #pragma unroll
    for (int mt = 0; mt < 4; ++mt) acc[mt] = (f32x4){0.f, 0.f, 0.f, 0.f};
    for (int k0 = 0; k0 < 512; k0 += 64) {
        __syncthreads();
        #pragma unroll
        for (int it = 0; it < 2; ++it) {
            const int q = tid + it * 256;
            const int row = q >> 3, c8 = (q & 7) * 8;
            *(uint4*)&As[row][c8] = *(const uint4*)&Xb[(size_t)(m0 + row) * 512 + k0 + c8];
            *(uint4*)&Bs[row][c8] = *(const uint4*)&WT[(size_t)(n0 + row) * 512 + k0 + c8];
        }
        __syncthreads();
        #pragma unroll
        for (int kt = 0; kt < 2; ++kt) {
            const bf16x8 b8 = *(const bf16x8*)&Bs[w * 16 + l16][kt * 32 + quad * 8];
            #pragma unroll
            for (int mt = 0; mt < 4; ++mt) {
                const bf16x8 a8 = *(const bf16x8*)&As[mt * 16 + l16][kt * 32 + quad * 8];
                acc[mt] = __builtin_amdgcn_mfma_f32_16x16x32_bf16(a8, b8, acc[mt], 0, 0, 0);
            }
        }
    }
    if (z == 2) {
        #pragma unroll
        for (int mt = 0; mt < 4; ++mt)
            #pragma unroll
            for (int r = 0; r < 4; ++r) {
                float v = acc[mt][r];
                v += __shfl_xor(v, 1, 64); v += __shfl_xor(v, 2, 64);
                v += __shfl_xor(v, 4, 64); v += __shfl_xor(v, 8, 64);
                if (l16 == 0) sRS[w][mt * 16 + quad * 4 + r] = v;
            }
        __syncthreads();
        if (tid < 64) {
            const float s = sRS[0][tid] + sRS[1][tid] + sRS[2][tid] + sRS[3][tid];
            const int m = m0 + tid, b = m >> 7, tl = m & 127, h = n0 >> 6;
            rr[(b * NH + h) * T + tl] = s;
        }
        return;
    }
    const int n = n0 + w * 16 + l16;
    const int h = n >> 6, d = n & 63;
    #pragma unroll
    for (int mt = 0; mt < 4; ++mt) {
        #pragma unroll
        for (int r = 0; r < 4; ++r) {
            const int m = m0 + mt * 16 + quad * 4 + r;
            const int b = m >> 7, t = m & 127;
            const size_t hm = (size_t)(b * NH + h) * T + t;
            const float v = acc[mt][r];
            if (z == 0)      p0b[hm * HS + d] = bfc(v);
            else if (z == 1) p1b[hm * HS + d] = bfc(v);
            else if (z == 3) V0[hm * HS + d] = v;
            else             V1T[((size_t)(b * NH + h) * HS + d) * T + t] = bfc(v);
        }
    }
}

// ---------------- main attention: one block per (bh, i), S-row via MFMA ----------------
__global__ __launch_bounds__(256) void attn_kernel(
    const unsigned short* __restrict__ p0b, const unsigned short* __restrict__ p1b,
    const float* __restrict__ rr, const float* __restrict__ V0g,
    const unsigned short* __restrict__ V1Tg, unsigned short* __restrict__ Yb)
{
    __shared__ __align__(16) unsigned short sE[128 * 128];  // 32 KB, xor-swizzled 16B chunks
    __shared__ float sS[128];
    __shared__ float srr[128];
    __shared__ float sM[4];
    __shared__ float sZ[4];

    const int blk = blockIdx.x;
    const int bh = blk & (BH - 1);
    const int i = (T - 1) - (blk >> 5);     // descending i: big blocks first
    const int tid = threadIdx.x;
    const int w = tid >> 6;
    const int lane = tid & 63;
    const int quad = lane >> 4;
    const int l16 = lane & 15;

    // stage r
    if (tid < 128) srr[tid] = rr[bh * T + tid];

    // V1 B-fragments in registers: wave w covers d = w*16+l16
    uint4 v1r[4];
    {
        const unsigned short* src = V1Tg + ((size_t)bh * HS + (w << 4) + l16) * T + (quad << 3);
        #pragma unroll
        for (int kt = 0; kt < 4; ++kt) v1r[kt] = *(const uint4*)(src + (kt << 5));
    }

    // S row i via MFMA: A = broadcast p0[i] (all 16 m-rows identical),
    // B = p1 rows direct-from-global. Wave w computes S cols [32w, 32w+32).
    {
        const unsigned short* ap = p0b + ((size_t)bh * T + i) * HS + (quad << 3);
        const unsigned short* bp = p1b + (size_t)bh * T * HS + (quad << 3);
        f32x4 s0 = (f32x4){0.f, 0.f, 0.f, 0.f};
        f32x4 s1 = (f32x4){0.f, 0.f, 0.f, 0.f};
        #pragma unroll
        for (int kt = 0; kt < 2; ++kt) {
            const bf16x8 a8 = *(const bf16x8*)(ap + (kt << 5));
            const bf16x8 b0 = *(const bf16x8*)(bp + (size_t)((w << 5) + l16) * HS + (kt << 5));
            const bf16x8 b1 = *(const bf16x8*)(bp + (size_t)((w << 5) + 16 + l16) * HS + (kt << 5));
            s0 = __builtin_amdgcn_mfma_f32_16x16x32_bf16(a8, b0, s0, 0, 0, 0);
            s1 = __builtin_amdgcn_mfma_f32_16x16x32_bf16(a8, b1, s1, 0, 0, 0);
        }
        if (quad == 0) {
            sS[(w << 5) + l16]      = s0[0] * 0.125f;
            sS[(w << 5) + 16 + l16] = s1[0] * 0.125f;
        }
    }
    __syncthreads();                                       // bar1: srr, sS ready

    // per-thread prefix max/min over srr[0..tid] (wave-uniform broadcast reads,
    // independent loads -> pipelined; trivially correct, no cross-wave handoff)
    float px = -INFINITY, pn = INFINITY;
    if (tid < 128) {
        for (int k = 0; k <= tid; ++k) {
            const float v = srr[k];
            px = fmaxf(px, v);
            pn = fminf(pn, v);
        }
    }
    const float2 rv = *(const float2*)&srr[2 * lane];

    // exact max m = max_{j<=i} (S_j>=0 ? S_j*prefmax_j : S_j*prefmin_j)
    float cand = -INFINITY;
    if (tid <= i) {
        const float Sj = sS[tid];
        cand = (Sj >= 0.f) ? Sj * px : Sj * pn;
    }
    #pragma unroll
    for (int off = 32; off; off >>= 1) cand = fmaxf(cand, __shfl_xor(cand, off, 64));
    if (lane == 0) sM[w] = cand;
    __syncthreads();                                       // bar2: sM ready
    const float m = fmaxf(fmaxf(sM[0], sM[1]), fmaxf(sM[2], sM[3]));

    // E-build: lane owns cols (2l, 2l+1); rows w, w+4, ..; swizzled 16B-chunk writes
    const float L2E = 1.4426950408889634f;
    const float bexp = -m * L2E;
    const int mtmax = i >> 4;
    const int jmax = (mtmax << 4) + 15;
    const int k0 = 2 * lane, k1 = k0 + 1;
    const int inoff = (lane & 3) << 2;
    const int chunkb = lane >> 2;
    float zacc = 0.f;
    for (int jj = w; jj <= jmax; jj += 4) {
        unsigned int pk = 0;
        if (jj <= i) {
            const float aL = sS[jj] * L2E;
            float e0 = __builtin_amdgcn_exp2f(fmaf(aL, rv.x, bexp));
            float e1 = __builtin_amdgcn_exp2f(fmaf(aL, rv.y, bexp));
            e0 = (k0 <= jj) ? e0 : 0.f;
            e1 = (k1 <= jj) ? e1 : 0.f;
            zacc += e0 + e1;
            pk = pk_bf16(e0, e1);
        }
        const int swz = chunkb ^ (jj & 15);
        *(unsigned int*)((char*)sE + (jj << 8) + (swz << 4) + inoff) = pk;
    }
    #pragma unroll
    for (int off = 32; off; off >>= 1) zacc += __shfl_xor(zacc, off, 64);
    if (lane == 0) sZ[w] = zacc;
    __syncthreads();                                       // bar3: sE, sZ ready
    const float Z = sZ[0] + sZ[1] + sZ[2] + sZ[3];

    // Tmat = E @ V1, triangular tiles; wave w covers d-cols [16w,16w+16)
    f32x4 acc[8];
    #pragma unroll
    for (int mt = 0; mt < 8; ++mt) acc[mt] = (f32x4){0.f, 0.f, 0.f, 0.f};
    #pragma unroll
    for (int mt = 0; mt < 8; ++mt) {
        if (mt <= mtmax) {
            #pragma unroll
            for (int kt = 0; kt <= (mt >> 1); ++kt) {
                const int swz = (4 * kt + quad) ^ l16;
                const bf16x8 a8 = *(const bf16x8*)((char*)sE + (((mt << 4) + l16) << 8) + (swz << 4));
                acc[mt] = __builtin_amdgcn_mfma_f32_16x16x32_bf16(
                    a8, __builtin_bit_cast(bf16x8, v1r[kt]), acc[mt], 0, 0, 0);
            }
        }
    }

    // epilogue: y[d] = sum_j V0[j][d] * Tmat[j][d] / Z
    const float* v0b = V0g + (size_t)bh * T * HS;
    const int d = (w << 4) + l16;
    float part = 0.f;
    #pragma unroll
    for (int mt = 0; mt < 8; ++mt) {
        if (mt <= mtmax) {
            #pragma unroll
            for (int r = 0; r < 4; ++r) {
                const int jr = (mt << 4) + (quad << 2) + r;
                if (jr <= i) part = fmaf(v0b[jr * HS + d], acc[mt][r], part);
            }
        }
    }
    part += __shfl_xor(part, 16, 64);
    part += __shfl_xor(part, 32, 64);
    if (lane < 16) {
        const int bb = bh >> 3, hh = bh & 7;
        Yb[((size_t)(bb * T + i) * C) + hh * HS + d] = bfc(part / Z);
    }
}

// ---------------- OUT = Yb @ Wc (bf16 MFMA, fp32 out) ----------------
__global__ __launch_bounds__(256) void outmm_kernel(
    const unsigned short* __restrict__ Ab, const unsigned short* __restrict__ WT,
    float* __restrict__ OUT)
{
    __shared__ __align__(16) unsigned short As[64][72];
    __shared__ __align__(16) unsigned short Bs[64][72];
    const int m0 = blockIdx.y * 64, n0 = blockIdx.x * 64;
    const int tid = threadIdx.x;
    const int w = tid >> 6, lane = tid & 63, quad = lane >> 4, l16 = lane & 15;
    f32x4 acc[4];
    #pragma unroll
    for (int mt = 0; mt < 4; ++mt) acc[mt] = (f32x4){0.f, 0.f, 0.f, 0.f};
    for (int k0 = 0; k0 < 512; k0 += 64) {
        __syncthreads();
        #pragma unroll
        for (int it = 0; it < 2; ++it) {
            const int q = tid + it * 256;
            const int row = q >> 3, c8 = (q & 7) * 8;
            *(uint4*)&As[row][c8] = *(const uint4*)&Ab[(size_t)(m0 + row) * 512 + k0 + c8];
            *(uint4*)&Bs[row][c8] = *(const uint4*)&WT[(size_t)(n0 + row) * 512 + k0 + c8];
        }
        __syncthreads();
        #pragma unroll
        for (int kt = 0; kt < 2; ++kt) {
            const bf16x8 b8 = *(const bf16x8*)&Bs[w * 16 + l16][kt * 32 + quad * 8];
            #pragma unroll
            for (int mt = 0; mt < 4; ++mt) {
                const bf16x8 a8 = *(const bf16x8*)&As[mt * 16 + l16][kt * 32 + quad * 8];
                acc[mt] = __builtin_amdgcn_mfma_f32_16x16x32_bf16(a8, b8, acc[mt], 0, 0, 0);
            }
        }
    }
    const int n = n0 + w * 16 + l16;
    #pragma unroll
    for (int mt = 0; mt < 4; ++mt)
        #pragma unroll
        for (int r = 0; r < 4; ++r) {
            const int mrow = m0 + mt * 16 + quad * 4 + r;
            OUT[(size_t)mrow * 512 + n] = acc[mt][r];
        }
}

extern "C" void kernel_launch(void* const* d_in, const int* in_sizes, int n_in,
                              void* d_out, int out_size, void* d_ws, size_t ws_size,
                              hipStream_t stream)
{
    const float* x   = (const float*)d_in[0];
    const float* Wp0 = (const float*)d_in[1];
    const float* Wp1 = (const float*)d_in[2];
    const float* Wp2 = (const float*)d_in[3];
    const float* Wv0 = (const float*)d_in[4];
    const float* Wv1 = (const float*)d_in[5];
    const float* Wc  = (const float*)d_in[6];
    float* out = (float*)d_out;

    char* w8 = (char*)d_ws;
    const size_t HB = 512 * 1024;
    unsigned short* Xb   = (unsigned short*)(w8 + 0 * HB);
    unsigned short* W0T  = (unsigned short*)(w8 + 1 * HB);
    unsigned short* W1T  = (unsigned short*)(w8 + 2 * HB);
    unsigned short* W2T  = (unsigned short*)(w8 + 3 * HB);
    unsigned short* WcT  = (unsigned short*)(w8 + 4 * HB);
    unsigned short* We0T = (unsigned short*)(w8 + 5 * HB);
    unsigned short* We1T = (unsigned short*)(w8 + 6 * HB);
    unsigned short* p0b  = (unsigned short*)(w8 + 7 * HB);
    unsigned short* p1b  = (unsigned short*)(w8 + 8 * HB);
    float*          V0   = (float*)        (w8 + 9 * HB);   // 1 MB
    unsigned short* V1T  = (unsigned short*)(w8 + 11 * HB);
    unsigned short* Yb   = (unsigned short*)(w8 + 12 * HB);
    float*          rr   = (float*)        (w8 + 13 * HB);

    prep_kernel  <<<dim3(8, 8, 7), 256, 0, stream>>>(x, Wp0, Wp1, Wp2, Wc, Wv0, Wv1,
                                                     Xb, W0T, W1T, W2T, WcT, We0T, We1T);
    projmm_kernel<<<dim3(8, 8, 5), 256, 0, stream>>>(Xb, W0T, W1T, W2T, We0T, We1T,
                                                     p0b, p1b, V0, V1T, rr);
    attn_kernel  <<<dim3(BH * T), 256, 0, stream>>>(p0b, p1b, rr, V0, V1T, Yb);
    outmm_kernel <<<dim3(8, 8), 256, 0, stream>>>(Yb, WcT, out);
}

// Round 8
// 122.867 us; speedup vs baseline: 1.1410x; 1.1410x over previous
//
#include <hip/hip_runtime.h>
#include <hip/hip_bf16.h>
#include <math.h>

#define B 4
#define T 128
#define C 512
#define NH 8
#define HS 64
#define BH (B*NH)   // 32

typedef __attribute__((ext_vector_type(8))) short bf16x8;
typedef __attribute__((ext_vector_type(4))) float f32x4;

__device__ __forceinline__ unsigned short bfc(float x) {
    return __builtin_bit_cast(unsigned short, __float2bfloat16(x));
}
__device__ __forceinline__ float b2f(unsigned short u) {
    unsigned int x = ((unsigned int)u) << 16;
    return __builtin_bit_cast(float, x);
}
__device__ __forceinline__ unsigned int pk_bf16(float a, float b) {
    return (unsigned int)bfc(a) | ((unsigned int)bfc(b) << 16);
}

// ---------------- prep: cvt X + transpose-cvt 4 weights + wcomb (2 slices) ----------------
__global__ __launch_bounds__(256) void prep_kernel(
    const float* __restrict__ X, const float* __restrict__ Wp0, const float* __restrict__ Wp1,
    const float* __restrict__ Wp2, const float* __restrict__ Wc,
    const float* __restrict__ Wv0, const float* __restrict__ Wv1,
    unsigned short* __restrict__ Xb, unsigned short* __restrict__ W0T, unsigned short* __restrict__ W1T,
    unsigned short* __restrict__ W2T, unsigned short* __restrict__ WcT,
    unsigned short* __restrict__ We0T, unsigned short* __restrict__ We1T)
{
    __shared__ float Ls[64][69];
    __shared__ float As[16][68];
    __shared__ float Bs[16][68];
    const int z = blockIdx.z;
    const int tid = threadIdx.x;
    if (z == 0) {
        const int r0 = blockIdx.y * 64, c0 = blockIdx.x * 64;
        #pragma unroll
        for (int it = 0; it < 2; ++it) {
            const int q = tid + it * 256;
            const int row = q >> 3, c8 = (q & 7) * 8;
            const float4 a = *(const float4*)&X[(size_t)(r0 + row) * 512 + c0 + c8];
            const float4 b = *(const float4*)&X[(size_t)(r0 + row) * 512 + c0 + c8 + 4];
            uint4 o;
            o.x = pk_bf16(a.x, a.y);
            o.y = pk_bf16(a.z, a.w);
            o.z = pk_bf16(b.x, b.y);
            o.w = pk_bf16(b.z, b.w);
            *(uint4*)&Xb[(size_t)(r0 + row) * 512 + c0 + c8] = o;
        }
        return;
    }
    if (z <= 4) {
        const int r0 = blockIdx.y * 64, c0 = blockIdx.x * 64;
        const float* W = (z == 1) ? Wp0 : (z == 2) ? Wp1 : (z == 3) ? Wp2 : Wc;
        unsigned short* WT = (z == 1) ? W0T : (z == 2) ? W1T : (z == 3) ? W2T : WcT;
        #pragma unroll
        for (int it = 0; it < 4; ++it) {
            const int q = tid + it * 256;
            const int row = q >> 4, c4 = (q & 15) * 4;
            const float4 v = *(const float4*)&W[(size_t)(r0 + row) * 512 + c0 + c4];
            Ls[row][c4 + 0] = v.x; Ls[row][c4 + 1] = v.y; Ls[row][c4 + 2] = v.z; Ls[row][c4 + 3] = v.w;
        }
        __syncthreads();
        #pragma unroll
        for (int it = 0; it < 2; ++it) {
            const int q = tid + it * 256;
            const int nrow = q >> 3, k8 = (q & 7) * 8;
            uint4 o;
            o.x = pk_bf16(Ls[k8 + 0][nrow], Ls[k8 + 1][nrow]);
            o.y = pk_bf16(Ls[k8 + 2][nrow], Ls[k8 + 3][nrow]);
            o.z = pk_bf16(Ls[k8 + 4][nrow], Ls[k8 + 5][nrow]);
            o.w = pk_bf16(Ls[k8 + 6][nrow], Ls[k8 + 7][nrow]);
            *(uint4*)&WT[(size_t)(c0 + nrow) * 512 + r0 + k8] = o;
        }
        return;
    }
    // z==5/6: We = Wp @ blockdiag(Wv), transposed bf16 out
    const float* A  = (z == 5) ? Wp1 : Wp2;
    const float* Wv = (z == 5) ? Wv0 : Wv1;
    unsigned short* O = (z == 5) ? We0T : We1T;
    const int h = blockIdx.x;
    const int m0 = blockIdx.y * 64;
    const int tx = tid & 15, ty = tid >> 4;
    const int arow = tid >> 2, acol = (tid & 3) * 4;
    const int brow = tid >> 4, bcol = (tid & 15) * 4;
    float acc[4][4] = {};
    for (int k0 = 0; k0 < 64; k0 += 16) {
        const float4 av = *(const float4*)&A[(size_t)(m0 + arow) * 512 + h * 64 + k0 + acol];
        const float4 bv = *(const float4*)&Wv[(size_t)(k0 + brow) * 64 + bcol];
        __syncthreads();
        As[acol + 0][arow] = av.x; As[acol + 1][arow] = av.y;
        As[acol + 2][arow] = av.z; As[acol + 3][arow] = av.w;
        *(float4*)&Bs[brow][bcol] = bv;
        __syncthreads();
        #pragma unroll
        for (int kk = 0; kk < 16; ++kk) {
            const float4 a4 = *(const float4*)&As[kk][ty * 4];
            const float4 b4 = *(const float4*)&Bs[kk][tx * 4];
            const float ar[4] = {a4.x, a4.y, a4.z, a4.w};
            const float br[4] = {b4.x, b4.y, b4.z, b4.w};
            #pragma unroll
            for (int r = 0; r < 4; ++r)
                #pragma unroll
                for (int c = 0; c < 4; ++c)
                    acc[r][c] = fmaf(ar[r], br[c], acc[r][c]);
        }
    }
    #pragma unroll
    for (int r = 0; r < 4; ++r)
        #pragma unroll
        for (int c = 0; c < 4; ++c)
            O[(size_t)(h * 64 + tx * 4 + c) * 512 + (m0 + ty * 4 + r)] = bfc(acc[r][c]);
}

// ---------------- bf16 MFMA projection GEMM; z==2 emits rowsums rr, never stores p2 ----------------
__global__ __launch_bounds__(256) void projmm_kernel(
    const unsigned short* __restrict__ Xb,
    const unsigned short* __restrict__ W0T, const unsigned short* __restrict__ W1T,
    const unsigned short* __restrict__ W2T,
    const unsigned short* __restrict__ We0T, const unsigned short* __restrict__ We1T,
    unsigned short* __restrict__ p0b, unsigned short* __restrict__ p1b,
    float* __restrict__ V0, unsigned short* __restrict__ V1T, float* __restrict__ rr)
{
    __shared__ __align__(16) unsigned short As[64][72];
    __shared__ __align__(16) unsigned short Bs[64][72];
    __shared__ float sRS[4][64];
    const int z = blockIdx.z;
    const unsigned short* WT = (z == 0) ? W0T : (z == 1) ? W1T : (z == 2) ? W2T : (z == 3) ? We0T : We1T;
    const int m0 = blockIdx.y * 64, n0 = blockIdx.x * 64;
    const int tid = threadIdx.x;
    const int w = tid >> 6, lane = tid & 63, quad = lane >> 4, l16 = lane & 15;
    f32x4 acc[4];
    #pragma unroll
    for (int mt = 0; mt < 4; ++mt) acc[mt] = (f32x4){0.f, 0.f, 0.f, 0.f};
    for (int k0 = 0; k0 < 512; k0 += 64) {
        __syncthreads();
        #pragma unroll
        for (int it = 0; it < 2; ++it) {
            const int q = tid + it * 256;
            const int row = q >> 3, c8 = (q & 7) * 8;
            *(uint4*)&As[row][c8] = *(const uint4*)&Xb[(size_t)(m0 + row) * 512 + k0 + c8];
            *(uint4*)&Bs[row][c8] = *(const uint4*)&WT[(size_t)(n0 + row) * 512 + k0 + c8];
        }
        __syncthreads();
        #pragma unroll
        for (int kt = 0; kt < 2; ++kt) {
            const bf16x8 b8 = *(const bf16x8*)&Bs[w * 16 + l16][kt * 32 + quad * 8];
            #pragma unroll
            for (int mt = 0; mt < 4; ++mt) {
                const bf16x8 a8 = *(const bf16x8*)&As[mt * 16 + l16][kt * 32 + quad * 8];
                acc[mt] = __builtin_amdgcn_mfma_f32_16x16x32_bf16(a8, b8, acc[mt], 0, 0, 0);
            }
        }
    }
    if (z == 2) {
        #pragma unroll
        for (int mt = 0; mt < 4; ++mt)
            #pragma unroll
            for (int r = 0; r < 4; ++r) {
                float v = acc[mt][r];
                v += __shfl_xor(v, 1, 64); v += __shfl_xor(v, 2, 64);
                v += __shfl_xor(v, 4, 64); v += __shfl_xor(v, 8, 64);
                if (l16 == 0) sRS[w][mt * 16 + quad * 4 + r] = v;
            }
        __syncthreads();
        if (tid < 64) {
            const float s = sRS[0][tid] + sRS[1][tid] + sRS[2][tid] + sRS[3][tid];
            const int m = m0 + tid, b = m >> 7, tl = m & 127, h = n0 >> 6;
            rr[(b * NH + h) * T + tl] = s;
        }
        return;
    }
    const int n = n0 + w * 16 + l16;
    const int h = n >> 6, d = n & 63;
    #pragma unroll
    for (int mt = 0; mt < 4; ++mt) {
        #pragma unroll
        for (int r = 0; r < 4; ++r) {
            const int m = m0 + mt * 16 + quad * 4 + r;
            const int b = m >> 7, t = m & 127;
            const size_t hm = (size_t)(b * NH + h) * T + t;
            const float v = acc[mt][r];
            if (z == 0)      p0b[hm * HS + d] = bfc(v);
            else if (z == 1) p1b[hm * HS + d] = bfc(v);
            else if (z == 3) V0[hm * HS + d] = v;
            else             V1T[((size_t)(b * NH + h) * HS + d) * T + t] = bfc(v);
        }
    }
}

// ---------------- main attention: one block per (bh, i) ----------------
// Softmax max via upper bound mhat = max|S| * max|r|  (softmax shift-invariant;
// mhat - m_true <= ~15 here, so exp scale >= 1e-7 -- far from underflow).
__global__ __launch_bounds__(256) void attn_kernel(
    const unsigned short* __restrict__ p0b, const unsigned short* __restrict__ p1b,
    const float* __restrict__ rr, const float* __restrict__ V0g,
    const unsigned short* __restrict__ V1Tg, unsigned short* __restrict__ Yb)
{
    __shared__ __align__(16) unsigned short sE[128 * 128];  // 32 KB, xor-swizzled 16B chunks
    __shared__ float sS[128];
    __shared__ float srr[128];
    __shared__ float sMS[4];
    __shared__ float sMR[4];
    __shared__ float sZ[4];

    const int blk = blockIdx.x;
    const int bh = blk & (BH - 1);
    const int i = (T - 1) - (blk >> 5);     // descending i: big blocks first
    const int tid = threadIdx.x;
    const int w = tid >> 6;
    const int lane = tid & 63;
    const int quad = lane >> 4;
    const int l16 = lane & 15;

    // stage r
    if (tid < 128) srr[tid] = rr[bh * T + tid];

    // V1 B-fragments in registers: wave w covers d = w*16+l16
    uint4 v1r[4];
    {
        const unsigned short* src = V1Tg + ((size_t)bh * HS + (w << 4) + l16) * T + (quad << 3);
        #pragma unroll
        for (int kt = 0; kt < 4; ++kt) v1r[kt] = *(const uint4*)(src + (kt << 5));
    }

    // S row i via MFMA: A = broadcast p0[i]; B = p1 rows direct-from-global.
    {
        const unsigned short* ap = p0b + ((size_t)bh * T + i) * HS + (quad << 3);
        const unsigned short* bp = p1b + (size_t)bh * T * HS + (quad << 3);
        f32x4 s0 = (f32x4){0.f, 0.f, 0.f, 0.f};
        f32x4 s1 = (f32x4){0.f, 0.f, 0.f, 0.f};
        #pragma unroll
        for (int kt = 0; kt < 2; ++kt) {
            const bf16x8 a8 = *(const bf16x8*)(ap + (kt << 5));
            const bf16x8 b0 = *(const bf16x8*)(bp + (size_t)((w << 5) + l16) * HS + (kt << 5));
            const bf16x8 b1 = *(const bf16x8*)(bp + (size_t)((w << 5) + 16 + l16) * HS + (kt << 5));
            s0 = __builtin_amdgcn_mfma_f32_16x16x32_bf16(a8, b0, s0, 0, 0, 0);
            s1 = __builtin_amdgcn_mfma_f32_16x16x32_bf16(a8, b1, s1, 0, 0, 0);
        }
        if (quad == 0) {
            sS[(w << 5) + l16]      = s0[0] * 0.125f;
            sS[(w << 5) + 16 + l16] = s1[0] * 0.125f;
        }
    }
    __syncthreads();                                       // bar1: srr, sS ready

    // joint abs-max of S and r over [0..i]
    float aS = 0.f, aR = 0.f;
    if (tid <= i) {
        aS = fabsf(sS[tid]);
        aR = fabsf(srr[tid]);
    }
    #pragma unroll
    for (int off = 32; off; off >>= 1) {
        aS = fmaxf(aS, __shfl_xor(aS, off, 64));
        aR = fmaxf(aR, __shfl_xor(aR, off, 64));
    }
    if (lane == 0) { sMS[w] = aS; sMR[w] = aR; }

    // per-thread r chunk (cc fixed): srr[8cc .. 8cc+8)
    const int cc = tid & 15;          // 16B chunk index within row
    const int rowin = tid >> 4;       // row within 16-row pass
    float rk[8];
    __syncthreads();                                       // bar2: sMS/sMR ready
    *(float4*)&rk[0] = *(const float4*)&srr[cc * 8];
    *(float4*)&rk[4] = *(const float4*)&srr[cc * 8 + 4];
    const float mS = fmaxf(fmaxf(sMS[0], sMS[1]), fmaxf(sMS[2], sMS[3]));
    const float mR = fmaxf(fmaxf(sMR[0], sMR[1]), fmaxf(sMR[2], sMR[3]));
    const float mhat = mS * mR;

    // E-build by (row, 16B-chunk): one ds_write_b128 per chunk, swizzle cc^(jj&15)
    const float L2E = 1.4426950408889634f;
    const float bexp = -mhat * L2E;
    const int mtmax = i >> 4;
    float zacc = 0.f;
    for (int p = 0; p <= mtmax; ++p) {
        const int jj = (p << 4) + rowin;
        uint4 o = {0u, 0u, 0u, 0u};
        if (jj <= i && (cc << 3) <= jj) {
            const float aL = sS[jj] * L2E;
            const int dlim = jj - (cc << 3);               // mask: q <= dlim
            float e[8];
            #pragma unroll
            for (int q = 0; q < 8; ++q) {
                const float ex = __builtin_amdgcn_exp2f(fmaf(aL, rk[q], bexp));
                e[q] = (q <= dlim) ? ex : 0.f;
                zacc += e[q];
            }
            o.x = pk_bf16(e[0], e[1]);
            o.y = pk_bf16(e[2], e[3]);
            o.z = pk_bf16(e[4], e[5]);
            o.w = pk_bf16(e[6], e[7]);
        }
        *(uint4*)((char*)sE + (jj << 8) + ((cc ^ (jj & 15)) << 4)) = o;
    }
    #pragma unroll
    for (int off = 32; off; off >>= 1) zacc += __shfl_xor(zacc, off, 64);
    if (lane == 0) sZ[w] = zacc;
    __syncthreads();                                       // bar3: sE, sZ ready
    const float Z = sZ[0] + sZ[1] + sZ[2] + sZ[3];

    // Tmat = E @ V1, triangular tiles; wave w covers d-cols [16w,16w+16)
    f32x4 acc[8];
    #pragma unroll
    for (int mt = 0; mt < 8; ++mt) acc[mt] = (f32x4){0.f, 0.f, 0.f, 0.f};
    #pragma unroll
    for (int mt = 0; mt < 8; ++mt) {
        if (mt <= mtmax) {
            #pragma unroll
            for (int kt = 0; kt <= (mt >> 1); ++kt) {
                const int swz = (4 * kt + quad) ^ l16;
                const bf16x8 a8 = *(const bf16x8*)((char*)sE + (((mt << 4) + l16) << 8) + (swz << 4));
                acc[mt] = __builtin_amdgcn_mfma_f32_16x16x32_bf16(
                    a8, __builtin_bit_cast(bf16x8, v1r[kt]), acc[mt], 0, 0, 0);
            }
        }
    }

    // epilogue: y[d] = sum_j V0[j][d] * Tmat[j][d] / Z  (mask only the boundary tile)
    const float* v0b = V0g + (size_t)bh * T * HS;
    const int d = (w << 4) + l16;
    float part = 0.f;
    #pragma unroll
    for (int mt = 0; mt < 8; ++mt) {
        if (mt < mtmax) {
            #pragma unroll
            for (int r = 0; r < 4; ++r) {
                const int jr = (mt << 4) + (quad << 2) + r;
                part = fmaf(v0b[jr * HS + d], acc[mt][r], part);
            }
        } else if (mt == mtmax) {
            #pragma unroll
            for (int r = 0; r < 4; ++r) {
                const int jr = (mt << 4) + (quad << 2) + r;
                if (jr <= i) part = fmaf(v0b[jr * HS + d], acc[mt][r], part);
            }
        }
    }
    part += __shfl_xor(part, 16, 64);
    part += __shfl_xor(part, 32, 64);
    if (lane < 16) {
        const int bb = bh >> 3, hh = bh & 7;
        Yb[((size_t)(bb * T + i) * C) + hh * HS + d] = bfc(part / Z);
    }
}

// ---------------- OUT = Yb @ Wc (bf16 MFMA, fp32 out) ----------------
__global__ __launch_bounds__(256) void outmm_kernel(
    const unsigned short* __restrict__ Ab, const unsigned short* __restrict__ WT,
    float* __restrict__ OUT)
{
    __shared__ __align__(16) unsigned short As[64][72];
    __shared__ __align__(16) unsigned short Bs[64][72];
    const int m0 = blockIdx.y * 64, n0 = blockIdx.x * 64;
    const int tid = threadIdx.x;
    const int w = tid >> 6, lane = tid & 63, quad = lane >> 4, l16 = lane & 15;
    f32x4 acc[4];
    #pragma unroll
    for (int mt = 0; mt < 4; ++mt) acc[mt] = (f32x4){0.f, 0.f, 0.f, 0.f};
    for (int k0 = 0; k0 < 512; k0 += 64) {
        __syncthreads();
        #pragma unroll
        for (int it = 0; it < 2; ++it) {
            const int q = tid + it * 256;
            const int row = q >> 3, c8 = (q & 7) * 8;
            *(uint4*)&As[row][c8] = *(const uint4*)&Ab[(size_t)(m0 + row) * 512 + k0 + c8];
            *(uint4*)&Bs[row][c8] = *(const uint4*)&WT[(size_t)(n0 + row) * 512 + k0 + c8];
        }
        __syncthreads();
        #pragma unroll
        for (int kt = 0; kt < 2; ++kt) {
            const bf16x8 b8 = *(const bf16x8*)&Bs[w * 16 + l16][kt * 32 + quad * 8];
            #pragma unroll
            for (int mt = 0; mt < 4; ++mt) {
                const bf16x8 a8 = *(const bf16x8*)&As[mt * 16 + l16][kt * 32 + quad * 8];
                acc[mt] = __builtin_amdgcn_mfma_f32_16x16x32_bf16(a8, b8, acc[mt], 0, 0, 0);
            }
        }
    }
    const int n = n0 + w * 16 + l16;
    #pragma unroll
    for (int mt = 0; mt < 4; ++mt)
        #pragma unroll
        for (int r = 0; r < 4; ++r) {
            const int mrow = m0 + mt * 16 + quad * 4 + r;
            OUT[(size_t)mrow * 512 + n] = acc[mt][r];
        }
}

extern "C" void kernel_launch(void* const* d_in, const int* in_sizes, int n_in,
                              void* d_out, int out_size, void* d_ws, size_t ws_size,
                              hipStream_t stream)
{
    const float* x   = (const float*)d_in[0];
    const float* Wp0 = (const float*)d_in[1];
    const float* Wp1 = (const float*)d_in[2];
    const float* Wp2 = (const float*)d_in[3];
    const float* Wv0 = (const float*)d_in[4];
    const float* Wv1 = (const float*)d_in[5];
    const float* Wc  = (const float*)d_in[6];
    float* out = (float*)d_out;

    char* w8 = (char*)d_ws;
    const size_t HB = 512 * 1024;
    unsigned short* Xb   = (unsigned short*)(w8 + 0 * HB);
    unsigned short* W0T  = (unsigned short*)(w8 + 1 * HB);
    unsigned short* W1T  = (unsigned short*)(w8 + 2 * HB);
    unsigned short* W2T  = (unsigned short*)(w8 + 3 * HB);
    unsigned short* WcT  = (unsigned short*)(w8 + 4 * HB);
    unsigned short* We0T = (unsigned short*)(w8 + 5 * HB);
    unsigned short* We1T = (unsigned short*)(w8 + 6 * HB);
    unsigned short* p0b  = (unsigned short*)(w8 + 7 * HB);
    unsigned short* p1b  = (unsigned short*)(w8 + 8 * HB);
    float*          V0   = (float*)        (w8 + 9 * HB);   // 1 MB
    unsigned short* V1T  = (unsigned short*)(w8 + 11 * HB);
    unsigned short* Yb   = (unsigned short*)(w8 + 12 * HB);
    float*          rr   = (float*)        (w8 + 13 * HB);

    prep_kernel  <<<dim3(8, 8, 7), 256, 0, stream>>>(x, Wp0, Wp1, Wp2, Wc, Wv0, Wv1,
                                                     Xb, W0T, W1T, W2T, WcT, We0T, We1T);
    projmm_kernel<<<dim3(8, 8, 5), 256, 0, stream>>>(Xb, W0T, W1T, W2T, We0T, We1T,
                                                     p0b, p1b, V0, V1T, rr);
    attn_kernel  <<<dim3(BH * T), 256, 0, stream>>>(p0b, p1b, rr, V0, V1T, Yb);
    outmm_kernel <<<dim3(8, 8), 256, 0, stream>>>(Yb, WcT, out);
}

// Round 9
// 122.745 us; speedup vs baseline: 1.1421x; 1.0010x over previous
//
#include <hip/hip_runtime.h>
#include <hip/hip_bf16.h>
#include <math.h>

#define B 4
#define T 128
#define C 512
#define NH 8
#define HS 64
#define BH (B*NH)   // 32

typedef __attribute__((ext_vector_type(8))) short bf16x8;
typedef __attribute__((ext_vector_type(4))) float f32x4;

__device__ __forceinline__ unsigned short bfc(float x) {
    return __builtin_bit_cast(unsigned short, __float2bfloat16(x));
}
__device__ __forceinline__ float b2f(unsigned short u) {
    unsigned int x = ((unsigned int)u) << 16;
    return __builtin_bit_cast(float, x);
}
__device__ __forceinline__ unsigned int pk_bf16(float a, float b) {
    return (unsigned int)bfc(a) | ((unsigned int)bfc(b) << 16);
}
__device__ __forceinline__ float lo_f(unsigned int g) {
    return __builtin_bit_cast(float, g << 16);
}
__device__ __forceinline__ float hi_f(unsigned int g) {
    return __builtin_bit_cast(float, g & 0xffff0000u);
}

// ---------------- prep: cvt X + transpose-cvt 4 weights + wcomb (2 slices) ----------------
__global__ __launch_bounds__(256) void prep_kernel(
    const float* __restrict__ X, const float* __restrict__ Wp0, const float* __restrict__ Wp1,
    const float* __restrict__ Wp2, const float* __restrict__ Wc,
    const float* __restrict__ Wv0, const float* __restrict__ Wv1,
    unsigned short* __restrict__ Xb, unsigned short* __restrict__ W0T, unsigned short* __restrict__ W1T,
    unsigned short* __restrict__ W2T, unsigned short* __restrict__ WcT,
    unsigned short* __restrict__ We0T, unsigned short* __restrict__ We1T)
{
    __shared__ float Ls[64][69];
    __shared__ float As[16][68];
    __shared__ float Bs[16][68];
    const int z = blockIdx.z;
    const int tid = threadIdx.x;
    if (z == 0) {
        const int r0 = blockIdx.y * 64, c0 = blockIdx.x * 64;
        #pragma unroll
        for (int it = 0; it < 2; ++it) {
            const int q = tid + it * 256;
            const int row = q >> 3, c8 = (q & 7) * 8;
            const float4 a = *(const float4*)&X[(size_t)(r0 + row) * 512 + c0 + c8];
            const float4 b = *(const float4*)&X[(size_t)(r0 + row) * 512 + c0 + c8 + 4];
            uint4 o;
            o.x = pk_bf16(a.x, a.y);
            o.y = pk_bf16(a.z, a.w);
            o.z = pk_bf16(b.x, b.y);
            o.w = pk_bf16(b.z, b.w);
            *(uint4*)&Xb[(size_t)(r0 + row) * 512 + c0 + c8] = o;
        }
        return;
    }
    if (z <= 4) {
        const int r0 = blockIdx.y * 64, c0 = blockIdx.x * 64;
        const float* W = (z == 1) ? Wp0 : (z == 2) ? Wp1 : (z == 3) ? Wp2 : Wc;
        unsigned short* WT = (z == 1) ? W0T : (z == 2) ? W1T : (z == 3) ? W2T : WcT;
        #pragma unroll
        for (int it = 0; it < 4; ++it) {
            const int q = tid + it * 256;
            const int row = q >> 4, c4 = (q & 15) * 4;
            const float4 v = *(const float4*)&W[(size_t)(r0 + row) * 512 + c0 + c4];
            Ls[row][c4 + 0] = v.x; Ls[row][c4 + 1] = v.y; Ls[row][c4 + 2] = v.z; Ls[row][c4 + 3] = v.w;
        }
        __syncthreads();
        #pragma unroll
        for (int it = 0; it < 2; ++it) {
            const int q = tid + it * 256;
            const int nrow = q >> 3, k8 = (q & 7) * 8;
            uint4 o;
            o.x = pk_bf16(Ls[k8 + 0][nrow], Ls[k8 + 1][nrow]);
            o.y = pk_bf16(Ls[k8 + 2][nrow], Ls[k8 + 3][nrow]);
            o.z = pk_bf16(Ls[k8 + 4][nrow], Ls[k8 + 5][nrow]);
            o.w = pk_bf16(Ls[k8 + 6][nrow], Ls[k8 + 7][nrow]);
            *(uint4*)&WT[(size_t)(c0 + nrow) * 512 + r0 + k8] = o;
        }
        return;
    }
    // z==5/6: We = Wp @ blockdiag(Wv), transposed bf16 out
    const float* A  = (z == 5) ? Wp1 : Wp2;
    const float* Wv = (z == 5) ? Wv0 : Wv1;
    unsigned short* O = (z == 5) ? We0T : We1T;
    const int h = blockIdx.x;
    const int m0 = blockIdx.y * 64;
    const int tx = tid & 15, ty = tid >> 4;
    const int arow = tid >> 2, acol = (tid & 3) * 4;
    const int brow = tid >> 4, bcol = (tid & 15) * 4;
    float acc[4][4] = {};
    for (int k0 = 0; k0 < 64; k0 += 16) {
        const float4 av = *(const float4*)&A[(size_t)(m0 + arow) * 512 + h * 64 + k0 + acol];
        const float4 bv = *(const float4*)&Wv[(size_t)(k0 + brow) * 64 + bcol];
        __syncthreads();
        As[acol + 0][arow] = av.x; As[acol + 1][arow] = av.y;
        As[acol + 2][arow] = av.z; As[acol + 3][arow] = av.w;
        *(float4*)&Bs[brow][bcol] = bv;
        __syncthreads();
        #pragma unroll
        for (int kk = 0; kk < 16; ++kk) {
            const float4 a4 = *(const float4*)&As[kk][ty * 4];
            const float4 b4 = *(const float4*)&Bs[kk][tx * 4];
            const float ar[4] = {a4.x, a4.y, a4.z, a4.w};
            const float br[4] = {b4.x, b4.y, b4.z, b4.w};
            #pragma unroll
            for (int r = 0; r < 4; ++r)
                #pragma unroll
                for (int c = 0; c < 4; ++c)
                    acc[r][c] = fmaf(ar[r], br[c], acc[r][c]);
        }
    }
    #pragma unroll
    for (int r = 0; r < 4; ++r)
        #pragma unroll
        for (int c = 0; c < 4; ++c)
            O[(size_t)(h * 64 + tx * 4 + c) * 512 + (m0 + ty * 4 + r)] = bfc(acc[r][c]);
}

// ---------------- bf16 MFMA projection GEMM; z==2 emits rowsums rr, never stores p2 ----------------
__global__ __launch_bounds__(256) void projmm_kernel(
    const unsigned short* __restrict__ Xb,
    const unsigned short* __restrict__ W0T, const unsigned short* __restrict__ W1T,
    const unsigned short* __restrict__ W2T,
    const unsigned short* __restrict__ We0T, const unsigned short* __restrict__ We1T,
    unsigned short* __restrict__ p0b, unsigned short* __restrict__ p1b,
    unsigned short* __restrict__ V0T, unsigned short* __restrict__ V1T, float* __restrict__ rr)
{
    __shared__ __align__(16) unsigned short As[64][72];
    __shared__ __align__(16) unsigned short Bs[64][72];
    __shared__ float sRS[4][64];
    const int z = blockIdx.z;
    const unsigned short* WT = (z == 0) ? W0T : (z == 1) ? W1T : (z == 2) ? W2T : (z == 3) ? We0T : We1T;
    const int m0 = blockIdx.y * 64, n0 = blockIdx.x * 64;
    const int tid = threadIdx.x;
    const int w = tid >> 6, lane = tid & 63, quad = lane >> 4, l16 = lane & 15;
    f32x4 acc[4];
    #pragma unroll
    for (int mt = 0; mt < 4; ++mt) acc[mt] = (f32x4){0.f, 0.f, 0.f, 0.f};
    for (int k0 = 0; k0 < 512; k0 += 64) {
        __syncthreads();
        #pragma unroll
        for (int it = 0; it < 2; ++it) {
            const int q = tid + it * 256;
            const int row = q >> 3, c8 = (q & 7) * 8;
            *(uint4*)&As[row][c8] = *(const uint4*)&Xb[(size_t)(m0 + row) * 512 + k0 + c8];
            *(uint4*)&Bs[row][c8] = *(const uint4*)&WT[(size_t)(n0 + row) * 512 + k0 + c8];
        }
        __syncthreads();
        #pragma unroll
        for (int kt = 0; kt < 2; ++kt) {
            const bf16x8 b8 = *(const bf16x8*)&Bs[w * 16 + l16][kt * 32 + quad * 8];
            #pragma unroll
            for (int mt = 0; mt < 4; ++mt) {
                const bf16x8 a8 = *(const bf16x8*)&As[mt * 16 + l16][kt * 32 + quad * 8];
                acc[mt] = __builtin_amdgcn_mfma_f32_16x16x32_bf16(a8, b8, acc[mt], 0, 0, 0);
            }
        }
    }
    if (z == 2) {
        #pragma unroll
        for (int mt = 0; mt < 4; ++mt)
            #pragma unroll
            for (int r = 0; r < 4; ++r) {
                float v = acc[mt][r];
                v += __shfl_xor(v, 1, 64); v += __shfl_xor(v, 2, 64);
                v += __shfl_xor(v, 4, 64); v += __shfl_xor(v, 8, 64);
                if (l16 == 0) sRS[w][mt * 16 + quad * 4 + r] = v;
            }
        __syncthreads();
        if (tid < 64) {
            const float s = sRS[0][tid] + sRS[1][tid] + sRS[2][tid] + sRS[3][tid];
            const int m = m0 + tid, b = m >> 7, tl = m & 127, h = n0 >> 6;
            rr[(b * NH + h) * T + tl] = s;
        }
        return;
    }
    const int n = n0 + w * 16 + l16;
    const int h = n >> 6, d = n & 63;
    #pragma unroll
    for (int mt = 0; mt < 4; ++mt) {
        #pragma unroll
        for (int r = 0; r < 4; ++r) {
            const int m = m0 + mt * 16 + quad * 4 + r;
            const int b = m >> 7, t = m & 127;
            const size_t hm = (size_t)(b * NH + h) * T + t;
            const float v = acc[mt][r];
            if (z == 0)      p0b[hm * HS + d] = bfc(v);
            else if (z == 1) p1b[hm * HS + d] = bfc(v);
            else if (z == 3) V0T[((size_t)(b * NH + h) * HS + d) * T + t] = bfc(v);
            else             V1T[((size_t)(b * NH + h) * HS + d) * T + t] = bfc(v);
        }
    }
}

// ---------------- main attention: one block per (bh, i); 2-panel E (16 KB) ----------------
// mhat = max|S| * max|r| upper bound (softmax shift-invariant; no underflow risk here).
__global__ __launch_bounds__(256) void attn_kernel(
    const unsigned short* __restrict__ p0b, const unsigned short* __restrict__ p1b,
    const float* __restrict__ rr, const unsigned short* __restrict__ V0Tg,
    const unsigned short* __restrict__ V1Tg, unsigned short* __restrict__ Yb)
{
    __shared__ __align__(16) unsigned short sE[128 * 64];   // 16 KB, xor-swizzled 16B chunks
    __shared__ float sS[128];
    __shared__ float srr[128];
    __shared__ float sZ[4];

    const int blk = blockIdx.x;
    const int bh = blk & (BH - 1);
    const int i = (T - 1) - (blk >> 5);     // descending i: big blocks first
    const int tid = threadIdx.x;
    const int w = tid >> 6;
    const int lane = tid & 63;
    const int quad = lane >> 4;
    const int l16 = lane & 15;

    // stage r
    if (tid < 128) srr[tid] = rr[bh * T + tid];

    // V1 B-fragments in registers: wave w covers d = w*16+l16
    uint4 v1r[4];
    {
        const unsigned short* src = V1Tg + ((size_t)bh * HS + (w << 4) + l16) * T + (quad << 3);
        #pragma unroll
        for (int kt = 0; kt < 4; ++kt) v1r[kt] = *(const uint4*)(src + (kt << 5));
    }

    // S row i via MFMA: A = broadcast p0[i]; B = p1 rows direct-from-global.
    {
        const unsigned short* ap = p0b + ((size_t)bh * T + i) * HS + (quad << 3);
        const unsigned short* bp = p1b + (size_t)bh * T * HS + (quad << 3);
        f32x4 s0 = (f32x4){0.f, 0.f, 0.f, 0.f};
        f32x4 s1 = (f32x4){0.f, 0.f, 0.f, 0.f};
        #pragma unroll
        for (int kt = 0; kt < 2; ++kt) {
            const bf16x8 a8 = *(const bf16x8*)(ap + (kt << 5));
            const bf16x8 b0 = *(const bf16x8*)(bp + (size_t)((w << 5) + l16) * HS + (kt << 5));
            const bf16x8 b1 = *(const bf16x8*)(bp + (size_t)((w << 5) + 16 + l16) * HS + (kt << 5));
            s0 = __builtin_amdgcn_mfma_f32_16x16x32_bf16(a8, b0, s0, 0, 0, 0);
            s1 = __builtin_amdgcn_mfma_f32_16x16x32_bf16(a8, b1, s1, 0, 0, 0);
        }
        if (quad == 0) {
            sS[(w << 5) + l16]      = s0[0] * 0.125f;
            sS[(w << 5) + 16 + l16] = s1[0] * 0.125f;
        }
    }
    __syncthreads();                                       // bar1: srr, sS ready

    // mhat: each wave computes the full [0..i] abs-max itself (no barrier, no LDS handoff)
    float mhat;
    {
        float s0 = (lane <= i) ? fabsf(sS[lane]) : 0.f;
        float s1 = (64 + lane <= i) ? fabsf(sS[64 + lane]) : 0.f;
        float r0 = (lane <= i) ? fabsf(srr[lane]) : 0.f;
        float r1 = (64 + lane <= i) ? fabsf(srr[64 + lane]) : 0.f;
        float aS = fmaxf(s0, s1), aR = fmaxf(r0, r1);
        #pragma unroll
        for (int off = 32; off; off >>= 1) {
            aS = fmaxf(aS, __shfl_xor(aS, off, 64));
            aR = fmaxf(aR, __shfl_xor(aR, off, 64));
        }
        mhat = aS * aR;
    }

    const float L2E = 1.4426950408889634f;
    const float bexp = -mhat * L2E;
    const int mtmax = i >> 4;
    const int cc = tid & 7;           // 16B chunk (8 bf16 cols) within panel
    const int rowin = tid >> 3;       // row within 32-row pass
    const int k0l = cc << 3;          // panel-local k base
    float zacc = 0.f;

    // ---- panel 0 build: cols k in [0,64), rows 0..(32*npass0-1) ----
    float rk[8];
    *(float4*)&rk[0] = *(const float4*)&srr[k0l];
    *(float4*)&rk[4] = *(const float4*)&srr[k0l + 4];
    const int npass0 = (mtmax >> 1) + 1;
    for (int p = 0; p < npass0; ++p) {
        const int jj = (p << 5) + rowin;
        uint4 o = {0u, 0u, 0u, 0u};
        if (jj <= i && k0l <= jj) {
            const float aL = sS[jj] * L2E;
            const int dlim = jj - k0l;
            float e[8];
            #pragma unroll
            for (int q = 0; q < 8; ++q) {
                const float ex = __builtin_amdgcn_exp2f(fmaf(aL, rk[q], bexp));
                e[q] = (q <= dlim) ? ex : 0.f;
                zacc += e[q];
            }
            o.x = pk_bf16(e[0], e[1]);
            o.y = pk_bf16(e[2], e[3]);
            o.z = pk_bf16(e[4], e[5]);
            o.w = pk_bf16(e[6], e[7]);
        }
        *(uint4*)&sE[(jj << 6) + ((cc ^ (jj & 7)) << 3)] = o;
    }

    f32x4 acc[8];
    #pragma unroll
    for (int mt = 0; mt < 8; ++mt) acc[mt] = (f32x4){0.f, 0.f, 0.f, 0.f};

    if (mtmax < 4) {
        // single-panel path: Z, one barrier, MFMA kt=0..1
        #pragma unroll
        for (int off = 32; off; off >>= 1) zacc += __shfl_xor(zacc, off, 64);
        if (lane == 0) sZ[w] = zacc;
        __syncthreads();                                   // bar2: E0 + Z ready
        #pragma unroll
        for (int mt = 0; mt < 4; ++mt) {
            if (mt <= mtmax) {
                #pragma unroll
                for (int kt = 0; kt <= 1; ++kt) {
                    if (kt <= (mt >> 1)) {
                        const int swz = ((kt << 2) + quad) ^ (l16 & 7);
                        const bf16x8 a8 = *(const bf16x8*)&sE[(((mt << 4) + l16) << 6) + (swz << 3)];
                        acc[mt] = __builtin_amdgcn_mfma_f32_16x16x32_bf16(
                            a8, __builtin_bit_cast(bf16x8, v1r[kt]), acc[mt], 0, 0, 0);
                    }
                }
            }
        }
    } else {
        __syncthreads();                                   // bar2: E0 ready
        // MFMA panel 0: kt = 0,1 for all row-tiles
        #pragma unroll
        for (int mt = 0; mt < 8; ++mt) {
            if (mt <= mtmax) {
                #pragma unroll
                for (int kt = 0; kt <= 1; ++kt) {
                    if (kt <= (mt >> 1)) {
                        const int swz = ((kt << 2) + quad) ^ (l16 & 7);
                        const bf16x8 a8 = *(const bf16x8*)&sE[(((mt << 4) + l16) << 6) + (swz << 3)];
                        acc[mt] = __builtin_amdgcn_mfma_f32_16x16x32_bf16(
                            a8, __builtin_bit_cast(bf16x8, v1r[kt]), acc[mt], 0, 0, 0);
                    }
                }
            }
        }
        __syncthreads();                                   // bar3: panel-0 reads drained
        // ---- panel 1 build: cols k in [64,128), rows 64.. ----
        *(float4*)&rk[0] = *(const float4*)&srr[64 + k0l];
        *(float4*)&rk[4] = *(const float4*)&srr[64 + k0l + 4];
        const int npass1 = ((mtmax - 4) >> 1) + 1;
        for (int p = 0; p < npass1; ++p) {
            const int jj = 64 + (p << 5) + rowin;
            uint4 o = {0u, 0u, 0u, 0u};
            if (jj <= i && 64 + k0l <= jj) {
                const float aL = sS[jj] * L2E;
                const int dlim = jj - 64 - k0l;
                float e[8];
                #pragma unroll
                for (int q = 0; q < 8; ++q) {
                    const float ex = __builtin_amdgcn_exp2f(fmaf(aL, rk[q], bexp));
                    e[q] = (q <= dlim) ? ex : 0.f;
                    zacc += e[q];
                }
                o.x = pk_bf16(e[0], e[1]);
                o.y = pk_bf16(e[2], e[3]);
                o.z = pk_bf16(e[4], e[5]);
                o.w = pk_bf16(e[6], e[7]);
            }
            *(uint4*)&sE[(jj << 6) + ((cc ^ (jj & 7)) << 3)] = o;
        }
        #pragma unroll
        for (int off = 32; off; off >>= 1) zacc += __shfl_xor(zacc, off, 64);
        if (lane == 0) sZ[w] = zacc;
        __syncthreads();                                   // bar4: E1 + Z ready
        // MFMA panel 1: kt = 2,3 for row-tiles >= 4
        #pragma unroll
        for (int mt = 4; mt < 8; ++mt) {
            if (mt <= mtmax) {
                #pragma unroll
                for (int kt = 2; kt <= 3; ++kt) {
                    if (kt <= (mt >> 1)) {
                        const int swz = (((kt & 1) << 2) + quad) ^ (l16 & 7);
                        const bf16x8 a8 = *(const bf16x8*)&sE[(((mt << 4) + l16) << 6) + (swz << 3)];
                        acc[mt] = __builtin_amdgcn_mfma_f32_16x16x32_bf16(
                            a8, __builtin_bit_cast(bf16x8, v1r[kt]), acc[mt], 0, 0, 0);
                    }
                }
            }
        }
    }
    const float Z = sZ[0] + sZ[1] + sZ[2] + sZ[3];

    // epilogue: y[d] = sum_j V0[j][d] * Tmat[j][d] / Z; V0T bf16 [d][t] -> 8B loads
    const unsigned short* v0t = V0Tg + ((size_t)bh * HS + (w << 4) + l16) * T;
    float part = 0.f;
    #pragma unroll
    for (int mt = 0; mt < 8; ++mt) {
        if (mt < mtmax) {
            const uint2 u = *(const uint2*)&v0t[(mt << 4) + (quad << 2)];
            part = fmaf(lo_f(u.x), acc[mt][0], part);
            part = fmaf(hi_f(u.x), acc[mt][1], part);
            part = fmaf(lo_f(u.y), acc[mt][2], part);
            part = fmaf(hi_f(u.y), acc[mt][3], part);
        } else if (mt == mtmax) {
            const uint2 u = *(const uint2*)&v0t[(mt << 4) + (quad << 2)];
            const int jb = (mt << 4) + (quad << 2);
            if (jb + 0 <= i) part = fmaf(lo_f(u.x), acc[mt][0], part);
            if (jb + 1 <= i) part = fmaf(hi_f(u.x), acc[mt][1], part);
            if (jb + 2 <= i) part = fmaf(lo_f(u.y), acc[mt][2], part);
            if (jb + 3 <= i) part = fmaf(hi_f(u.y), acc[mt][3], part);
        }
    }
    part += __shfl_xor(part, 16, 64);
    part += __shfl_xor(part, 32, 64);
    if (lane < 16) {
        const int bb = bh >> 3, hh = bh & 7;
        Yb[((size_t)(bb * T + i) * C) + hh * HS + (w << 4) + l16] = bfc(part / Z);
    }
}

// ---------------- OUT = Yb @ Wc (bf16 MFMA, fp32 out) ----------------
__global__ __launch_bounds__(256) void outmm_kernel(
    const unsigned short* __restrict__ Ab, const unsigned short* __restrict__ WT,
    float* __restrict__ OUT)
{
    __shared__ __align__(16) unsigned short As[64][72];
    __shared__ __align__(16) unsigned short Bs[64][72];
    const int m0 = blockIdx.y * 64, n0 = blockIdx.x * 64;
    const int tid = threadIdx.x;
    const int w = tid >> 6, lane = tid & 63, quad = lane >> 4, l16 = lane & 15;
    f32x4 acc[4];
    #pragma unroll
    for (int mt = 0; mt < 4; ++mt) acc[mt] = (f32x4){0.f, 0.f, 0.f, 0.f};
    for (int k0 = 0; k0 < 512; k0 += 64) {
        __syncthreads();
        #pragma unroll
        for (int it = 0; it < 2; ++it) {
            const int q = tid + it * 256;
            const int row = q >> 3, c8 = (q & 7) * 8;
            *(uint4*)&As[row][c8] = *(const uint4*)&Ab[(size_t)(m0 + row) * 512 + k0 + c8];
            *(uint4*)&Bs[row][c8] = *(const uint4*)&WT[(size_t)(n0 + row) * 512 + k0 + c8];
        }
        __syncthreads();
        #pragma unroll
        for (int kt = 0; kt < 2; ++kt) {
            const bf16x8 b8 = *(const bf16x8*)&Bs[w * 16 + l16][kt * 32 + quad * 8];
            #pragma unroll
            for (int mt = 0; mt < 4; ++mt) {
                const bf16x8 a8 = *(const bf16x8*)&As[mt * 16 + l16][kt * 32 + quad * 8];
                acc[mt] = __builtin_amdgcn_mfma_f32_16x16x32_bf16(a8, b8, acc[mt], 0, 0, 0);
            }
        }
    }
    const int n = n0 + w * 16 + l16;
    #pragma unroll
    for (int mt = 0; mt < 4; ++mt)
        #pragma unroll
        for (int r = 0; r < 4; ++r) {
            const int mrow = m0 + mt * 16 + quad * 4 + r;
            OUT[(size_t)mrow * 512 + n] = acc[mt][r];
        }
}

extern "C" void kernel_launch(void* const* d_in, const int* in_sizes, int n_in,
                              void* d_out, int out_size, void* d_ws, size_t ws_size,
                              hipStream_t stream)
{
    const float* x   = (const float*)d_in[0];
    const float* Wp0 = (const float*)d_in[1];
    const float* Wp1 = (const float*)d_in[2];
    const float* Wp2 = (const float*)d_in[3];
    const float* Wv0 = (const float*)d_in[4];
    const float* Wv1 = (const float*)d_in[5];
    const float* Wc  = (const float*)d_in[6];
    float* out = (float*)d_out;

    char* w8 = (char*)d_ws;
    const size_t HB = 512 * 1024;
    unsigned short* Xb   = (unsigned short*)(w8 + 0 * HB);
    unsigned short* W0T  = (unsigned short*)(w8 + 1 * HB);
    unsigned short* W1T  = (unsigned short*)(w8 + 2 * HB);
    unsigned short* W2T  = (unsigned short*)(w8 + 3 * HB);
    unsigned short* WcT  = (unsigned short*)(w8 + 4 * HB);
    unsigned short* We0T = (unsigned short*)(w8 + 5 * HB);
    unsigned short* We1T = (unsigned short*)(w8 + 6 * HB);
    unsigned short* p0b  = (unsigned short*)(w8 + 7 * HB);
    unsigned short* p1b  = (unsigned short*)(w8 + 8 * HB);
    unsigned short* V0T  = (unsigned short*)(w8 + 9 * HB);
    unsigned short* V1T  = (unsigned short*)(w8 + 10 * HB);
    unsigned short* Yb   = (unsigned short*)(w8 + 11 * HB);
    float*          rr   = (float*)        (w8 + 12 * HB);

    prep_kernel  <<<dim3(8, 8, 7), 256, 0, stream>>>(x, Wp0, Wp1, Wp2, Wc, Wv0, Wv1,
                                                     Xb, W0T, W1T, W2T, WcT, We0T, We1T);
    projmm_kernel<<<dim3(8, 8, 5), 256, 0, stream>>>(Xb, W0T, W1T, W2T, We0T, We1T,
                                                     p0b, p1b, V0T, V1T, rr);
    attn_kernel  <<<dim3(BH * T), 256, 0, stream>>>(p0b, p1b, rr, V0T, V1T, Yb);
    outmm_kernel <<<dim3(8, 8), 256, 0, stream>>>(Yb, WcT, out);
}